// Round 7
// baseline (621.857 us; speedup 1.0000x reference)
//
#include <hip/hip_runtime.h>

#define VOCAB 4096
#define SLICES 8
#define SLICE 512            // codes per slice (8-way split per point)
#define GRP 8                // codes per max-tree group
#define NGRP (SLICE / GRP)   // 64 groups per slice

// Empty-asm register barrier: forces the value into a VGPR, preventing
// fma-contraction / reassociation across it. Emits no instruction.
__device__ __forceinline__ float opaque(float x) {
  asm volatile("" : "+v"(x));
  return x;
}

// Prep: pack per-code {e0, e1, e2, h} into ws as float4 where
// h = -0.5f * c and c = ((e0*e0 + e1*e1) + e2*e2) rounded exactly like
// numpy (each product and sum individually rounded f32). h is an exact
// scale of c (exponent shift), so c = -2*h is recoverable bit-exactly.
// Also zero the loss slot.
__global__ __launch_bounds__(256) void vq_prep_kernel(
    const float* __restrict__ cb, float4* __restrict__ cw,
    float* __restrict__ loss_slot) {
  int j = blockIdx.x * 256 + threadIdx.x;
  if (j == 0) *loss_slot = 0.0f;
  if (j < VOCAB) {
    float e0 = cb[3 * j + 0];
    float e1 = cb[3 * j + 1];
    float e2 = cb[3 * j + 2];
    float p0 = opaque(e0 * e0);
    float p1 = opaque(e1 * e1);
    float p2 = opaque(e2 * e2);
    float c = opaque(opaque(p0 + p1) + p2);
    cw[j] = make_float4(e0, e1, e2, -0.5f * c);
  }
}

// Surrogate scan value: t = x.e - c/2 (3 fma). Exactly: a - 2*t == d.
// argmin d == argmax t up to rounding noise bounded by eps below.
__device__ __forceinline__ float tval(float x0, float x1, float x2,
                                      float4 cd) {
  return fmaf(x0, cd.x, fmaf(x1, cd.y, fmaf(x2, cd.z, cd.w)));
}

// Bit-exact numpy f32 distance:
//   m = x.e (fma ascending k, first term single-rounded mul)
//   d = (a - 2m) + c   [a-2m via fma(-2,m,a): 2m exact, value-identical]
__device__ __forceinline__ float dist_f32(float x0, float x1, float x2,
                                          float a, float4 cd) {
  float m = fmaf(x2, cd.z, fmaf(x1, cd.y, x0 * cd.x));
  return fmaf(-2.0f, m, a) + (-2.0f * cd.w);  // c = -2*h, bit-exact
}

// Main: block = 512 threads = 64 points x 8 codebook slices.
__global__ __launch_bounds__(512) void vq_kernel(
    const float* __restrict__ feats, const float4* __restrict__ cw,
    float* __restrict__ out_quant, float* __restrict__ out_idx,
    float* __restrict__ out_loss, int npts) {
  __shared__ float sT1[512];
  __shared__ float sT2[512];
  __shared__ int sG[512];
  __shared__ double sL[64];

  const int tid = threadIdx.x;
  const int lane = tid & 63;
  // slice id is wave-uniform; force SGPR so code records stream via s_load
  const int s = __builtin_amdgcn_readfirstlane(tid >> 6);
  const int p = blockIdx.x * 64 + lane;

  const float x0 = feats[3 * p + 0];
  const float x1 = feats[3 * p + 1];
  const float x2 = feats[3 * p + 2];

  // ||x||^2 exactly as numpy: products rounded, then ((p0+p1)+p2)
  float xp0 = opaque(x0 * x0);
  float xp1 = opaque(x1 * x1);
  float xp2 = opaque(x2 * x2);
  const float a = opaque(opaque(xp0 + xp1) + xp2);

  const float4* cs = cw + s * SLICE;

  // Scan: per group of 8, max-tree over t; track best group (t1, g1) and
  // the max over all OTHER groups t2 (for the safety margin test).
  float t1 = -3.4e38f, t2 = -3.4e38f;
  int g1 = 0;
#pragma unroll 2
  for (int g = 0; g < NGRP; ++g) {
    const float4* gp = cs + g * GRP;  // wave-uniform -> s_load_dwordx16 x2
    float u0 = tval(x0, x1, x2, gp[0]);
    float u1 = tval(x0, x1, x2, gp[1]);
    float u2 = tval(x0, x1, x2, gp[2]);
    float u3 = tval(x0, x1, x2, gp[3]);
    float u4 = tval(x0, x1, x2, gp[4]);
    float u5 = tval(x0, x1, x2, gp[5]);
    float u6 = tval(x0, x1, x2, gp[6]);
    float u7 = tval(x0, x1, x2, gp[7]);
    float gm = fmaxf(fmaxf(fmaxf(u0, u1), fmaxf(u2, u3)),
                     fmaxf(fmaxf(u4, u5), fmaxf(u6, u7)));
    // top-2 group tracking: t2 = max(t2, min(t1, gm)); strict > keeps
    // the EARLIEST group attaining the running max in g1.
    t2 = fmaxf(t2, fminf(t1, gm));
    if (gm > t1) g1 = g;
    t1 = fmaxf(t1, gm);
  }
  int gbase = s * SLICE + g1 * GRP;

  sT1[tid] = t1;
  sT2[tid] = t2;
  sG[tid] = gbase;
  __syncthreads();

  if (tid < 64) {
    // combine slices in ascending-index order
#pragma unroll
    for (int k = 1; k < SLICES; ++k) {
      float a1 = sT1[tid + 64 * k];
      float a2 = sT2[tid + 64 * k];
      t2 = fmaxf(t2, a2);
      t2 = fmaxf(t2, fminf(t1, a1));
      if (a1 > t1) gbase = sG[tid + 64 * k];
      t1 = fmaxf(t1, a1);
    }
    // Safety test: if the best group beats every other group by more than
    // the worst-case (surrogate vs numpy-f32) rounding discrepancy, the
    // numpy argmin is guaranteed inside gbase's 8 codes. Else rescan all.
    // eps >= 4x the derived bound (2a+3)*2^-24 + 4e-7.
    float eps = fmaf(a, 0x1p-21f, 0x1p-19f);
    bool fb = !((t1 - t2) > eps);
    int base = fb ? 0 : gbase;
    int cnt = fb ? VOCAB : GRP;
    // Bit-exact rescan, ascending index, strict <: np.argmin first-min.
    float bd = 3.4e38f;
    int bi = 0;
    float q0 = 0.0f, q1 = 0.0f, q2 = 0.0f;
    for (int k = 0; k < cnt; ++k) {
      float4 cd = cw[base + k];
      float d = dist_f32(x0, x1, x2, a, cd);
      if (d < bd) { bd = d; bi = base + k; q0 = cd.x; q1 = cd.y; q2 = cd.z; }
    }
    // straight-through: t = q - x (f32), out = x + t (f32), like reference
    float t0d = q0 - x0, t1d = q1 - x1, t2d = q2 - x2;
    out_quant[3 * p + 0] = x0 + t0d;
    out_quant[3 * p + 1] = x1 + t1d;
    out_quant[3 * p + 2] = x2 + t2d;
    out_idx[p] = (float)bi;
    sL[tid] = (double)t0d * t0d + (double)t1d * t1d + (double)t2d * t2d;
  }
  __syncthreads();

  if (tid == 0) {
    double acc = 0.0;
#pragma unroll 8
    for (int k = 0; k < 64; ++k) acc += sL[k];
    // loss = mean((q-x)^2) + 0.25*mean((x-q)^2) = 1.25 * sum / (npts*3)
    atomicAdd(out_loss, (float)(acc * (1.25 / ((double)npts * 3.0))));
  }
}

extern "C" void kernel_launch(void* const* d_in, const int* in_sizes, int n_in,
                              void* d_out, int out_size, void* d_ws,
                              size_t ws_size, hipStream_t stream) {
  const float* feats = (const float*)d_in[0];      // (B*L, 3) f32
  const float* cb = (const float*)d_in[1];         // (4096, 3) f32
  const int npts = in_sizes[0] / 3;                // 65536

  float* out = (float*)d_out;
  float* out_quant = out;                          // npts*3 elems
  float* out_idx = out + in_sizes[0];              // npts elems
  float* out_loss = out + in_sizes[0] + npts;      // 1 elem

  float4* cw = (float4*)d_ws;                      // 4096 * 16 B = 64 KB

  vq_prep_kernel<<<VOCAB / 256, 256, 0, stream>>>(cb, cw, out_loss);
  vq_kernel<<<npts / 64, 512, 0, stream>>>(feats, cw, out_quant, out_idx,
                                           out_loss, npts);
}

// Round 8
// 107.262 us; speedup vs baseline: 5.7976x; 5.7976x over previous
//
#include <hip/hip_runtime.h>

#define VOCAB 4096
#define SLICES 8
#define SLICE 512            // codes per slice (8-way split per point)
#define GRP 8                // codes per min-tree group
#define NGRP (SLICE / GRP)   // 64 groups per slice

// Empty-asm register barrier: forces the value into a VGPR, preventing
// fma-contraction / reassociation across it. Emits no instruction.
__device__ __forceinline__ float opaque(float x) {
  asm volatile("" : "+v"(x));
  return x;
}

// v_min3_f32: value-identical to fminf(fminf(a,b),c) for finite inputs
// (min is exact; no rounding). Compiler won't form min3 without nnan.
__device__ __forceinline__ float min3(float a, float b, float c) {
  float d;
  asm("v_min3_f32 %0, %1, %2, %3" : "=v"(d) : "v"(a), "v"(b), "v"(c));
  return d;
}

// Prep: pack per-code {e0, e1, e2, ||e||^2_f32} into ws as float4, where
// ||e||^2 is rounded exactly like numpy: ((e0*e0 + e1*e1) + e2*e2), each
// product and sum individually rounded in f32. Also zero the loss slot.
__global__ __launch_bounds__(256) void vq_prep_kernel(
    const float* __restrict__ cb, float4* __restrict__ cw,
    float* __restrict__ loss_slot) {
  int j = blockIdx.x * 256 + threadIdx.x;
  if (j == 0) *loss_slot = 0.0f;
  if (j < VOCAB) {
    float e0 = cb[3 * j + 0];
    float e1 = cb[3 * j + 1];
    float e2 = cb[3 * j + 2];
    float p0 = opaque(e0 * e0);
    float p1 = opaque(e1 * e1);
    float p2 = opaque(e2 * e2);
    float c = opaque(opaque(p0 + p1) + p2);
    cw[j] = make_float4(e0, e1, e2, c);
  }
}

// Distance with numpy's exact f32 rounding:
//   m = x.e (fma ascending k, first term single-rounded mul)
//   d = (a - 2m) + c   [a-2m via fma(-2,m,a): 2m is exact, value-identical]
__device__ __forceinline__ float dist_f32(float x0, float x1, float x2,
                                          float a, float4 cd) {
  float m = fmaf(x2, cd.z, fmaf(x1, cd.y, x0 * cd.x));
  return fmaf(-2.0f, m, a) + cd.w;
}

// Main: block = 512 threads = 64 points x 8 codebook slices.
// 1024 blocks x 8 waves -> up to 32 waves/CU.
__global__ __launch_bounds__(512) void vq_kernel(
    const float* __restrict__ feats, const float4* __restrict__ cw,
    float* __restrict__ out_quant, float* __restrict__ out_idx,
    float* __restrict__ out_loss, int npts) {
  __shared__ float sB[512];
  __shared__ int sI[512];
  __shared__ double sL[64];

  const int tid = threadIdx.x;
  const int lane = tid & 63;
  // slice id is wave-uniform; force SGPR so code records stream via s_load
  const int s = __builtin_amdgcn_readfirstlane(tid >> 6);
  const int p = blockIdx.x * 64 + lane;

  const float x0 = feats[3 * p + 0];
  const float x1 = feats[3 * p + 1];
  const float x2 = feats[3 * p + 2];

  // ||x||^2 exactly as numpy: products rounded, then ((p0+p1)+p2)
  float xp0 = opaque(x0 * x0);
  float xp1 = opaque(x1 * x1);
  float xp2 = opaque(x2 * x2);
  const float a = opaque(opaque(xp0 + xp1) + xp2);

  const float4* cs = cw + s * SLICE;

  // Group-min scan: track only (best value, winning group base).
  // All distances are >= (|x|-|e|)^2 >> 0: positive, no NaN -> min exact.
  float best = 3.4e38f;
  int gbase = 0;
#pragma unroll 2
  for (int g = 0; g < NGRP; ++g) {
    const float4* gp = cs + g * GRP;  // wave-uniform -> s_load_dwordx16 x2
    float d0 = dist_f32(x0, x1, x2, a, gp[0]);
    float d1 = dist_f32(x0, x1, x2, a, gp[1]);
    float d2 = dist_f32(x0, x1, x2, a, gp[2]);
    float d3 = dist_f32(x0, x1, x2, a, gp[3]);
    float d4 = dist_f32(x0, x1, x2, a, gp[4]);
    float d5 = dist_f32(x0, x1, x2, a, gp[5]);
    float d6 = dist_f32(x0, x1, x2, a, gp[6]);
    float d7 = dist_f32(x0, x1, x2, a, gp[7]);
    // 8-way min in 4 insts via v_min3; value == nested fminf tree
    float gm = min3(min3(d0, d1, d2), min3(d3, d4, d5), fminf(d6, d7));
    // strict <: keeps the EARLIEST group attaining the running min
    if (gm < best) gbase = g;
    best = fminf(best, gm);
  }
  gbase = s * SLICE + gbase * GRP;

  sB[tid] = best;
  sI[tid] = gbase;
  __syncthreads();

  if (tid < 64) {
    // combine slices in ascending-index order; strict < keeps earliest group
#pragma unroll
    for (int k = 1; k < SLICES; ++k) {
      float v = sB[tid + 64 * k];
      if (v < best) { best = v; gbase = sI[tid + 64 * k]; }
    }
    // Index recovery: rescan the winning 8-code group with identical
    // rounding; ascending, strict <: np.argmin's first-occurrence winner.
    int bi = gbase;
    float bd = 3.4e38f;
    float q0 = 0.0f, q1 = 0.0f, q2 = 0.0f;
#pragma unroll
    for (int k = 0; k < GRP; ++k) {
      float4 cd = cw[gbase + k];
      float d = dist_f32(x0, x1, x2, a, cd);
      if (d < bd) { bd = d; bi = gbase + k; q0 = cd.x; q1 = cd.y; q2 = cd.z; }
    }
    // straight-through: t = q - x (f32), out = x + t (f32), like reference
    float t0 = q0 - x0, t1 = q1 - x1, t2 = q2 - x2;
    out_quant[3 * p + 0] = x0 + t0;
    out_quant[3 * p + 1] = x1 + t1;
    out_quant[3 * p + 2] = x2 + t2;
    out_idx[p] = (float)bi;
    sL[tid] = (double)t0 * t0 + (double)t1 * t1 + (double)t2 * t2;
  }
  __syncthreads();

  if (tid == 0) {
    double acc = 0.0;
#pragma unroll 8
    for (int k = 0; k < 64; ++k) acc += sL[k];
    // loss = mean((q-x)^2) + 0.25*mean((x-q)^2) = 1.25 * sum / (npts*3)
    atomicAdd(out_loss, (float)(acc * (1.25 / ((double)npts * 3.0))));
  }
}

extern "C" void kernel_launch(void* const* d_in, const int* in_sizes, int n_in,
                              void* d_out, int out_size, void* d_ws,
                              size_t ws_size, hipStream_t stream) {
  const float* feats = (const float*)d_in[0];      // (B*L, 3) f32
  const float* cb = (const float*)d_in[1];         // (4096, 3) f32
  const int npts = in_sizes[0] / 3;                // 65536

  float* out = (float*)d_out;
  float* out_quant = out;                          // npts*3 elems
  float* out_idx = out + in_sizes[0];              // npts elems
  float* out_loss = out + in_sizes[0] + npts;      // 1 elem

  float4* cw = (float4*)d_ws;                      // 4096 * 16 B = 64 KB

  vq_prep_kernel<<<VOCAB / 256, 256, 0, stream>>>(cb, cw, out_loss);
  vq_kernel<<<npts / 64, 512, 0, stream>>>(feats, cw, out_quant, out_idx,
                                           out_loss, npts);
}